// Round 1
// baseline (952.544 us; speedup 1.0000x reference)
//
#include <hip/hip_runtime.h>
#include <stdint.h>

#define D_MODELC 512
#define N_HEADSC 8
#define DKH 64
#define BATCH 16
#define SEQ 1024
#define M_TOT (BATCH*SEQ)    // 16384
#define NBH (BATCH*N_HEADSC) // 128

typedef __attribute__((ext_vector_type(8))) short short8;
typedef __attribute__((ext_vector_type(4))) float float4v;
typedef __attribute__((ext_vector_type(4))) unsigned short ushort4v;

__device__ inline unsigned short f2bf(float f) {
    unsigned u = __float_as_uint(f);
    u += 0x7FFFu + ((u >> 16) & 1u);   // RNE
    return (unsigned short)(u >> 16);
}

__device__ inline void gl2lds16(const void* g, void* l) {
    __builtin_amdgcn_global_load_lds(
        (__attribute__((address_space(1))) void*)g,
        (__attribute__((address_space(3))) void*)l, 16, 0, 0);
}

// ---------------- kernel 0a: x fp32 -> bf16 ----------------
__global__ void k_cvt_x(const float* __restrict__ x, unsigned short* __restrict__ xb) {
    int i = (blockIdx.x * 256 + threadIdx.x) * 4;   // 8192 blocks * 1024 = 8388608 exact
    float4v v = *(const float4v*)(x + i);
    ushort4v o;
    o.x = f2bf(v.x); o.y = f2bf(v.y); o.z = f2bf(v.z); o.w = f2bf(v.w);
    *(ushort4v*)(xb + i) = o;
}

// ---------------- kernel 0b: W (K,N) fp32 -> Wt[n][k] bf16, LDS tile transpose --------
__global__ void k_wt(const float* __restrict__ Wq, const float* __restrict__ Wk,
                     const float* __restrict__ Wv, const float* __restrict__ Wo,
                     unsigned short* __restrict__ Wqkvt, unsigned short* __restrict__ Wot) {
    __shared__ float tile[32][33];
    const int blk = blockIdx.x;            // 1024 = 4 mats * 16 * 16 tiles
    const int mat = blk >> 8;
    const int t2  = blk & 255;
    const int kt = (t2 >> 4) * 32;         // row of W (input dim k)
    const int nt = (t2 & 15) * 32;         // col of W (output dim n)
    const float* W = mat == 0 ? Wq : mat == 1 ? Wk : mat == 2 ? Wv : Wo;
    const int tid = threadIdx.x;
    const int cx = tid & 31, ry = tid >> 5;   // 8 rows per pass
#pragma unroll
    for (int p = 0; p < 4; ++p) {
        int kr = ry + p * 8;
        tile[kr][cx] = W[(size_t)(kt + kr) * 512 + nt + cx];
    }
    __syncthreads();
    unsigned short* DST = (mat < 3) ? (Wqkvt + (size_t)mat * 512 * 512) : Wot;
#pragma unroll
    for (int p = 0; p < 4; ++p) {
        int nr = ry + p * 8;
        DST[(size_t)(nt + nr) * 512 + kt + cx] = f2bf(tile[cx][nr]);
    }
}

// ---------------- GEMM: C = A(bf16 M x512) @ Bt^T + bias ----------------
// MODE 0: A=xb, Bt=Wqkv_t[1536][512]; epilogue scatters Q(scaled)/K/Vt bf16.
// MODE 1: A=ctx, Bt=Wo_t[512][512]; epilogue writes fp32 out + bo.
template<int MODE>
__global__ __launch_bounds__(256, 2) void k_gemm(
    const unsigned short* __restrict__ A,
    const unsigned short* __restrict__ Bt,
    const float* __restrict__ bias0,
    const float* __restrict__ bias1,
    const float* __restrict__ bias2,
    unsigned short* __restrict__ Qb,
    unsigned short* __restrict__ Kb,
    unsigned short* __restrict__ Vtb,
    float* __restrict__ Out)
{
    __shared__ __align__(16) unsigned short As[128 * 32];
    __shared__ __align__(16) unsigned short Bs[128 * 32];
    const int m0 = blockIdx.y * 128;
    const int n0 = blockIdx.x * 128;
    const int tid = threadIdx.x;
    const int w = tid >> 6, l = tid & 63;
    const int lm = l & 15, q4 = l >> 4;
    const int wm = (w >> 1) * 64, wn = (w & 1) * 64;

    float4v acc[4][4] = {};

    for (int k0 = 0; k0 < 512; k0 += 32) {
#pragma unroll
        for (int r = 0; r < 2; ++r) {
            int e = tid * 8 + r * 2048;          // flat bf16 idx into 128x32 tile
            int row = e >> 5, col = e & 31;
            gl2lds16(A  + (size_t)(m0 + row) * 512 + k0 + col,
                     (char*)As + w * 1024 + r * 4096);
            gl2lds16(Bt + (size_t)(n0 + row) * 512 + k0 + col,
                     (char*)Bs + w * 1024 + r * 4096);
        }
        __syncthreads();
        short8 af[4], bfr[4];
#pragma unroll
        for (int mi = 0; mi < 4; ++mi)
            af[mi] = *(const short8*)(As + (wm + mi * 16 + lm) * 32 + q4 * 8);
#pragma unroll
        for (int ni = 0; ni < 4; ++ni)
            bfr[ni] = *(const short8*)(Bs + (wn + ni * 16 + lm) * 32 + q4 * 8);
#pragma unroll
        for (int mi = 0; mi < 4; ++mi)
#pragma unroll
            for (int ni = 0; ni < 4; ++ni)
                acc[mi][ni] = __builtin_amdgcn_mfma_f32_16x16x32_bf16(
                    af[mi], bfr[ni], acc[mi][ni], 0, 0, 0);
        __syncthreads();
    }

#pragma unroll
    for (int mi = 0; mi < 4; ++mi)
#pragma unroll
        for (int ni = 0; ni < 4; ++ni)
#pragma unroll
            for (int r = 0; r < 4; ++r) {
                int m = m0 + wm + mi * 16 + q4 * 4 + r;
                int n = n0 + wn + ni * 16 + lm;
                float v = acc[mi][ni][r];
                if (MODE == 0) {
                    int which = n >> 9;
                    int nn = n & 511;
                    int h = nn >> 6, d = nn & 63;
                    int b = m >> 10, s = m & 1023;
                    size_t qkoff = (((size_t)(b * N_HEADSC + h)) * SEQ + s) * DKH + d;
                    if (which == 0) {
                        v = (v + bias0[nn]) * 0.125f;    // fold 1/sqrt(dk), exact pow2
                        Qb[qkoff] = f2bf(v);
                    } else if (which == 1) {
                        Kb[qkoff] = f2bf(v + bias1[nn]);
                    } else {
                        Vtb[(((size_t)(b * N_HEADSC + h)) * DKH + d) * SEQ + s] =
                            f2bf(v + bias2[nn]);
                    }
                } else {
                    Out[(size_t)m * 512 + n] = v + bias0[n];
                }
            }
}

// ---------------- kernel 2: scores + softmax, write attn fp32 ----------------
// one block = 32 query rows of one (b,h); wave w owns key cols [w*256, w*256+256)
__global__ __launch_bounds__(256, 2) void k_attn(
    const unsigned short* __restrict__ Qb,
    const unsigned short* __restrict__ Kb,
    float* __restrict__ attn)
{
    __shared__ float wstat[4][32];
    const int blk = blockIdx.x;            // 4096 = 128 bh * 32 qtiles
    const int bh = blk >> 5;
    const int m0 = (blk & 31) * 32;
    const int tid = threadIdx.x;
    const int w = tid >> 6, l = tid & 63;
    const int lm = l & 15, q4 = l >> 4;
    const unsigned short* Qh = Qb + (size_t)bh * SEQ * DKH;
    const unsigned short* Kh = Kb + (size_t)bh * SEQ * DKH;
    const int nw0 = w * 256;

    short8 a[2][2];
#pragma unroll
    for (int mi = 0; mi < 2; ++mi)
#pragma unroll
        for (int ks = 0; ks < 2; ++ks)
            a[mi][ks] = *(const short8*)(Qh + (size_t)(m0 + mi * 16 + lm) * 64 + ks * 32 + q4 * 8);

    float4v acc[2][16];
#pragma unroll
    for (int cg = 0; cg < 16; ++cg) {
        const unsigned short* kp = Kh + (size_t)(nw0 + cg * 16 + lm) * 64 + q4 * 8;
        short8 b0 = *(const short8*)kp;
        short8 b1 = *(const short8*)(kp + 32);
#pragma unroll
        for (int mi = 0; mi < 2; ++mi) {
            float4v z = {0.f, 0.f, 0.f, 0.f};
            z = __builtin_amdgcn_mfma_f32_16x16x32_bf16(a[mi][0], b0, z, 0, 0, 0);
            acc[mi][cg] = __builtin_amdgcn_mfma_f32_16x16x32_bf16(a[mi][1], b1, z, 0, 0, 0);
        }
    }

    // ---- global row max ----
    float gM[2][4];
#pragma unroll
    for (int mi = 0; mi < 2; ++mi)
#pragma unroll
        for (int r = 0; r < 4; ++r) {
            float pm = -1e30f;
#pragma unroll
            for (int cg = 0; cg < 16; ++cg) pm = fmaxf(pm, acc[mi][cg][r]);
#pragma unroll
            for (int sh = 1; sh < 16; sh <<= 1) pm = fmaxf(pm, __shfl_xor(pm, sh));
            gM[mi][r] = pm;
        }
    if (lm == 0) {
#pragma unroll
        for (int mi = 0; mi < 2; ++mi)
#pragma unroll
            for (int r = 0; r < 4; ++r)
                wstat[w][mi * 16 + q4 * 4 + r] = gM[mi][r];
    }
    __syncthreads();
#pragma unroll
    for (int mi = 0; mi < 2; ++mi)
#pragma unroll
        for (int r = 0; r < 4; ++r) {
            int row = mi * 16 + q4 * 4 + r;
            gM[mi][r] = fmaxf(fmaxf(wstat[0][row], wstat[1][row]),
                              fmaxf(wstat[2][row], wstat[3][row]));
        }
    __syncthreads();

    // ---- exp + global row sum ----
    float gS[2][4];
#pragma unroll
    for (int mi = 0; mi < 2; ++mi)
#pragma unroll
        for (int r = 0; r < 4; ++r) {
            float ps = 0.f;
#pragma unroll
            for (int cg = 0; cg < 16; ++cg) {
                float e = __expf(acc[mi][cg][r] - gM[mi][r]);
                acc[mi][cg][r] = e;
                ps += e;
            }
#pragma unroll
            for (int sh = 1; sh < 16; sh <<= 1) ps += __shfl_xor(ps, sh);
            gS[mi][r] = ps;
        }
    if (lm == 0) {
#pragma unroll
        for (int mi = 0; mi < 2; ++mi)
#pragma unroll
            for (int r = 0; r < 4; ++r)
                wstat[w][mi * 16 + q4 * 4 + r] = gS[mi][r];
    }
    __syncthreads();
    float inv[2][4];
#pragma unroll
    for (int mi = 0; mi < 2; ++mi)
#pragma unroll
        for (int r = 0; r < 4; ++r) {
            int row = mi * 16 + q4 * 4 + r;
            inv[mi][r] = 1.f / (wstat[0][row] + wstat[1][row] + wstat[2][row] + wstat[3][row]);
        }

    const size_t base = (size_t)bh * SEQ * SEQ;
#pragma unroll
    for (int cg = 0; cg < 16; ++cg)
#pragma unroll
        for (int mi = 0; mi < 2; ++mi)
#pragma unroll
            for (int r = 0; r < 4; ++r)
                attn[base + (size_t)(m0 + mi * 16 + q4 * 4 + r) * SEQ + nw0 + cg * 16 + lm] =
                    acc[mi][cg][r] * inv[mi][r];
}

// ---------------- kernel 3: ctx = P @ V ----------------
// one block = 128 query rows of one (b,h); wave w owns rows [w*32, w*32+32), all 64 d
__global__ __launch_bounds__(256, 2) void k_pv(
    const float* __restrict__ attn,
    const unsigned short* __restrict__ Vtb,
    unsigned short* __restrict__ ctx)
{
    const int blk = blockIdx.x;          // 1024 = 128 bh * 8 mtiles
    const int bh = blk >> 3;
    const int m0 = (blk & 7) * 128;
    const int tid = threadIdx.x;
    const int w = tid >> 6, l = tid & 63;
    const int lm = l & 15, q4 = l >> 4;
    const float* Ph = attn + (size_t)bh * SEQ * SEQ;
    const unsigned short* Vh = Vtb + (size_t)bh * DKH * SEQ;
    const int wm = w * 32;

    float4v acc[2][4] = {};
    for (int kc = 0; kc < 1024; kc += 32) {
        short8 a[2];
#pragma unroll
        for (int mi = 0; mi < 2; ++mi) {
            const float* p = Ph + (size_t)(m0 + wm + mi * 16 + lm) * SEQ + kc + q4 * 8;
            float4v p0 = *(const float4v*)p;
            float4v p1 = *(const float4v*)(p + 4);
            short8 t;
            t[0] = (short)f2bf(p0.x); t[1] = (short)f2bf(p0.y);
            t[2] = (short)f2bf(p0.z); t[3] = (short)f2bf(p0.w);
            t[4] = (short)f2bf(p1.x); t[5] = (short)f2bf(p1.y);
            t[6] = (short)f2bf(p1.z); t[7] = (short)f2bf(p1.w);
            a[mi] = t;
        }
#pragma unroll
        for (int ni = 0; ni < 4; ++ni) {
            short8 bfr = *(const short8*)(Vh + (size_t)(ni * 16 + lm) * SEQ + kc + q4 * 8);
#pragma unroll
            for (int mi = 0; mi < 2; ++mi)
                acc[mi][ni] = __builtin_amdgcn_mfma_f32_16x16x32_bf16(a[mi], bfr, acc[mi][ni], 0, 0, 0);
        }
    }
    const int bb = bh >> 3, h = bh & 7;
#pragma unroll
    for (int mi = 0; mi < 2; ++mi)
#pragma unroll
        for (int ni = 0; ni < 4; ++ni)
#pragma unroll
            for (int r = 0; r < 4; ++r) {
                int s = m0 + wm + mi * 16 + q4 * 4 + r;
                int d = ni * 16 + lm;
                ctx[((size_t)(bb * SEQ + s)) * 512 + h * 64 + d] = f2bf(acc[mi][ni][r]);
            }
}

// ---------------- launch ----------------
extern "C" void kernel_launch(void* const* d_in, const int* in_sizes, int n_in,
                              void* d_out, int out_size, void* d_ws, size_t ws_size,
                              hipStream_t stream) {
    const float* x  = (const float*)d_in[0];
    const float* Wq = (const float*)d_in[1];
    const float* bq = (const float*)d_in[2];
    const float* Wk = (const float*)d_in[3];
    const float* bk = (const float*)d_in[4];
    const float* Wv = (const float*)d_in[5];
    const float* bv = (const float*)d_in[6];
    const float* Wo = (const float*)d_in[7];
    const float* bo = (const float*)d_in[8];

    float* out  = (float*)d_out;
    float* attn = out + (size_t)M_TOT * D_MODELC;   // second output, 134,217,728 floats

    char* ws = (char*)d_ws;
    unsigned short* xb    = (unsigned short*)(ws);                       // 16 MB
    unsigned short* Qb    = (unsigned short*)(ws + (size_t)(16u << 20)); // 16 MB [bh][s][d], pre-scaled
    unsigned short* Kb    = (unsigned short*)(ws + (size_t)(32u << 20)); // 16 MB [bh][s][d]
    unsigned short* Vtb   = (unsigned short*)(ws + (size_t)(48u << 20)); // 16 MB [bh][d][s]
    unsigned short* ctxb  = (unsigned short*)(ws + (size_t)(64u << 20)); // 16 MB [b*s][h*64+d]
    unsigned short* Wqkvt = (unsigned short*)(ws + (size_t)(80u << 20)); // 1.5 MB [1536][512]
    unsigned short* Wot   = (unsigned short*)(ws + (size_t)(82u << 20)); // 0.5 MB [512][512]

    k_cvt_x<<<8192, 256, 0, stream>>>(x, xb);
    k_wt<<<1024, 256, 0, stream>>>(Wq, Wk, Wv, Wo, Wqkvt, Wot);
    k_gemm<0><<<dim3(12, 128), 256, 0, stream>>>(xb, Wqkvt, bq, bk, bv,
                                                 Qb, Kb, Vtb, nullptr);
    k_attn<<<4096, 256, 0, stream>>>(Qb, Kb, attn);
    k_pv<<<1024, 256, 0, stream>>>(attn, Vtb, ctxb);
    k_gemm<1><<<dim3(4, 128), 256, 0, stream>>>(ctxb, Wot, bo, nullptr, nullptr,
                                                nullptr, nullptr, nullptr, out);
}